// Round 12
// baseline (266.478 us; speedup 1.0000x reference)
//
#include <hip/hip_runtime.h>
#include <hip/hip_fp16.h>
#include <cmath>

#define CAPB 64    // padded bucket capacity; deg~Poisson(16), P(>64)~1e-21; overflow list for safety
#define CAPF 88    // staged edge capacity in k_fused0 (bucket + overflow + pad-to-4)
#define CAP1 96    // staged edge capacity in k_fused1 (bucket + overflow + pad-to-16)
#define WA   92    // s_wa per-head stride in halfwords (even, bank-spreading)
#define G0_ROWS 32 // rows per GEMM block: best measured point (r6/r7: gemm0 < 72us)
#define G0_PAD 36  // k2-row stride in dwords (multiple of 4 for b128-aligned reads)
#define NSCAT 1024 // scatter blocks
#define PBLK 1024  // persistent blocks for fused kernels (4/CU x 256 CU)

typedef _Float16 h2v __attribute__((ext_vector_type(2)));

__device__ __forceinline__ float dot2a(unsigned f, unsigned w, float acc) {
  return __builtin_amdgcn_fdot2(__builtin_bit_cast(h2v, f),
                                __builtin_bit_cast(h2v, w), acc, false);
}
__device__ __forceinline__ unsigned pkh2(float lo, float hi) {
  return (unsigned)__half_as_ushort(__float2half_rn(lo)) |
         ((unsigned)__half_as_ushort(__float2half_rn(hi)) << 16);
}

// ---------------- prep: zero cnt + pack W0/W1 into fp16 k-pair dwords ------------
__global__ void k_prep(const float* __restrict__ W0, const float* __restrict__ W1,
                       unsigned* __restrict__ W0h, unsigned* __restrict__ W1ct,
                       int* __restrict__ cnt, int Np1) {
  int gid = blockIdx.x * 256 + threadIdx.x;
  int stride = gridDim.x * 256;
  for (int i = gid; i < Np1; i += stride) cnt[i] = 0;
  if (gid < 16384) {
    int k2 = gid >> 8, c = gid & 255;
    W0h[gid] = pkh2(W0[(size_t)(2 * k2) * 256 + c], W0[(size_t)(2 * k2 + 1) * 256 + c]);
  } else if (gid < 20480) {
    int j = gid - 16384;
    int c = j >> 7, k2 = j & 127;
    W1ct[j] = pkh2(W1[(size_t)(2 * k2) * 32 + c], W1[(size_t)(2 * k2 + 1) * 32 + c]);
  } else if (gid < 20992) {
    W0h[gid - 20992 + 16896] = 0;   // zero the 2-row prefetch pad (k2 rows 64,65)
  }
}

// ---------------- merged kernel: gemm blocks OR scatter blocks (disjoint) ----------
// First ngemm blocks: GEMM0 tile (32 rows) via fp16 v_dot2 (packed W0h + fp16-pair
// LDS x), k2 loop software-pipelined depth 2 for W0h. Remaining blocks: edge
// scatter. fp32 accumulate; f0 stored FP16; el/er from fp32 accumulators.
__global__ void k_gemm0_scatter(const float* __restrict__ x, const unsigned* __restrict__ W0h,
                                const float* __restrict__ al, const float* __restrict__ ar,
                                const int* __restrict__ dst, const int* __restrict__ src,
                                unsigned short* __restrict__ f0h, float* __restrict__ el,
                                float* __restrict__ er, int* __restrict__ cnt,
                                int* __restrict__ ovf_cnt, int* __restrict__ bpad,
                                int* __restrict__ ovf, int N, int E, int ngemm) {
  __shared__ unsigned s_x2[66 * G0_PAD];   // k2 rows 0..63 data; rows 64,65 = prefetch pad
  int t = threadIdx.x;

  if (blockIdx.x >= ngemm) {
    int nscat = gridDim.x - ngemm;
    for (int e = (blockIdx.x - ngemm) * blockDim.x + t; e < E; e += nscat * blockDim.x) {
      int d = dst[e];
      int pos = atomicAdd(&cnt[d], 1);
      if (pos < CAPB) bpad[(size_t)d * CAPB + pos] = src[e];
      else { int op = atomicAdd(ovf_cnt, 1); ovf[op] = e; }
    }
    return;
  }

  // ---- gemm0 tile: 32 rows x 256 cols ----
  int w = t >> 6, l = t & 63;
  int row0 = blockIdx.x * G0_ROWS;
  {
    int row = t & 31, cg = t >> 5;           // cg 0..7: 16 cols each
    int grow = row0 + row; if (grow >= N) grow = N - 1;
    const float* xp = x + (size_t)grow * 128 + cg * 16;
    int k2b = cg * 8;
#pragma unroll
    for (int j = 0; j < 4; ++j) {
      float4 v = *(const float4*)(xp + 4 * j);
      s_x2[(k2b + 2 * j) * G0_PAD + row] = pkh2(v.x, v.y);
      s_x2[(k2b + 2 * j + 1) * G0_PAD + row] = pkh2(v.z, v.w);
    }
  }
  __syncthreads();

  float4 acc[8];
#pragma unroll
  for (int r = 0; r < 8; ++r) acc[r] = make_float4(0.f, 0.f, 0.f, 0.f);

  const unsigned* wp = W0h + 4 * l;
  int rbase = w * 8;

#define LDX(dstv, kk)                                              \
  { const unsigned* xk_ = &s_x2[(kk) * G0_PAD + rbase];            \
    *(uint4*)&dstv[0]  = *(const uint4*)(xk_);                     \
    *(uint4*)&dstv[4]  = *(const uint4*)(xk_ + 4); }
#define DOTS(xv, w4)                                               \
  _Pragma("unroll")                                                \
  for (int r = 0; r < 8; ++r) {                                    \
    acc[r].x = dot2a(xv[r], w4.x, acc[r].x);                       \
    acc[r].y = dot2a(xv[r], w4.y, acc[r].y);                       \
    acc[r].z = dot2a(xv[r], w4.z, acc[r].z);                       \
    acc[r].w = dot2a(xv[r], w4.w, acc[r].w);                       \
  }

  unsigned xA[8], xB[8];
  uint4 wA = *(const uint4*)(wp);
  uint4 wB = *(const uint4*)(wp + 256);
  LDX(xA, 0);
#pragma unroll 2
  for (int k2 = 0; k2 < 64; k2 += 2) {
    uint4 wC = *(const uint4*)(wp + (size_t)(k2 + 2) * 256);  // pad rows safe
    uint4 wD = *(const uint4*)(wp + (size_t)(k2 + 3) * 256);
    LDX(xB, k2 + 1);
    DOTS(xA, wA);
    LDX(xA, k2 + 2);                                          // pad row safe in LDS
    DOTS(xB, wB);
    wA = wC; wB = wD;
  }
#undef LDX
#undef DOTS

  int hh = l >> 3;
  float4 al4 = *(const float4*)(al + 4 * l);
  float4 ar4 = *(const float4*)(ar + 4 * l);
#pragma unroll
  for (int r = 0; r < 8; ++r) {
    int row = row0 + rbase + r;
    float4 f = acc[r];
    if (row < N) {
      ushort4 h4;
      h4.x = __half_as_ushort(__float2half_rn(f.x));
      h4.y = __half_as_ushort(__float2half_rn(f.y));
      h4.z = __half_as_ushort(__float2half_rn(f.z));
      h4.w = __half_as_ushort(__float2half_rn(f.w));
      *(ushort4*)(f0h + (size_t)row * 256 + 4 * l) = h4;
    }
    float pl = fmaf(f.x, al4.x, fmaf(f.y, al4.y, fmaf(f.z, al4.z, f.w * al4.w)));
    float pr = fmaf(f.x, ar4.x, fmaf(f.y, ar4.y, fmaf(f.z, ar4.z, f.w * ar4.w)));
#pragma unroll
    for (int off = 4; off >= 1; off >>= 1) {
      pl += __shfl_xor(pl, off, 64);
      pr += __shfl_xor(pr, off, 64);
    }
    if ((l & 7) == 0 && row < N) {
      el[row * 8 + hh] = pl;
      er[row * 8 + hh] = pr;
    }
  }
}

// ---------------- fused edge kernel layer 0 + layer-1 projection -------------------
// PERSISTENT: 1024 blocks x 512 thr (4 blocks/CU, LDS-resident cap). One wave per
// node; each wave loops nodes with stride gridDim*8, prefetching the NEXT node's
// cnt + bucket row into registers so the ~400cy bucket latency hides under the
// current node's gather. No per-node barriers (all per-node LDS wave-private).
__global__ void k_fused0(const float* __restrict__ el, const float* __restrict__ er,
                         const unsigned short* __restrict__ f0h, const int* __restrict__ cnt,
                         const int* __restrict__ ovf_cnt, const int* __restrict__ bpad,
                         const int* __restrict__ ovf, const int* __restrict__ dstp,
                         const int* __restrict__ src, const float* __restrict__ b0,
                         const unsigned* __restrict__ W1ct, const float* __restrict__ al1,
                         const float* __restrict__ ar1, unsigned short* __restrict__ f1h,
                         float* __restrict__ el1, float* __restrict__ er1, int N) {
  __shared__ unsigned s_w1[32 * 132];          // 16896 B, W1 half2-pairs [c][k2], stride 132
  __shared__ unsigned short s_wa[8][8 * WA];   // 11776 B, fp16 softmax weights per node
  __shared__ int s_s[8][CAPF];                 //  2816 B, staged src ids per node
  __shared__ unsigned s_h2[8][128];            //  4096 B, fp16-packed h row per node

  const int t = threadIdx.x;
  // ---- stage packed W1 into LDS (pad stride 132 for bank spread) ----
  for (int base = t * 4; base < 4096; base += 2048) {
    uint4 v = *(const uint4*)&W1ct[base];
    int c = base >> 7, k2 = base & 127;
    *(uint4*)&s_w1[c * 132 + k2] = v;
  }
  __syncthreads();                              // ONLY barrier; safe before any exit

  const int w = __builtin_amdgcn_readfirstlane(t >> 6);
  const int l = t & 63;
  const int stride = gridDim.x * 8;
  int node = blockIdx.x * 8 + w;
  if (node >= N) return;

  int* sS = s_s[w];
  unsigned short* sWA = s_wa[w];

  const int sub = l & 31, half = l >> 5, hh = sub >> 2;
  // per-wave constant preloads (once per wave, not per node)
  float4 b0a = ((const float4*)(b0 + 8 * sub))[0];
  float4 b0b = ((const float4*)(b0 + 8 * sub))[1];
  float al1c = al1[sub], ar1c = ar1[sub];
  const int ovl = ovf_cnt[0];

  // ---- initial bucket prefetch ----
  int cur_cn = cnt[node];
  int cur_bp = bpad[(size_t)node * CAPB + l];

#define GLOAD(AA, BB, ii)                                              \
  { int2 s_ = *(const int2*)&sS[(ii) + 2 * half];                      \
    AA = ((const uint4*)(f0h + (size_t)s_.x * 256))[sub];              \
    BB = ((const uint4*)(f0h + (size_t)s_.y * 256))[sub]; }
#define GCOMP(AA, BB, ii)                                              \
  { unsigned wpk = *(const unsigned*)&sWA[hh * WA + (ii) + 2 * half];  \
    unsigned lo_, hi_;                                                 \
    lo_ = __builtin_amdgcn_perm(AA.x, BB.x, 0x01000504u);              \
    hi_ = __builtin_amdgcn_perm(AA.x, BB.x, 0x03020706u);              \
    a0 = dot2a(lo_, wpk, a0); a1 = dot2a(hi_, wpk, a1);                \
    lo_ = __builtin_amdgcn_perm(AA.y, BB.y, 0x01000504u);              \
    hi_ = __builtin_amdgcn_perm(AA.y, BB.y, 0x03020706u);              \
    a2 = dot2a(lo_, wpk, a2); a3 = dot2a(hi_, wpk, a3);                \
    lo_ = __builtin_amdgcn_perm(AA.z, BB.z, 0x01000504u);              \
    hi_ = __builtin_amdgcn_perm(AA.z, BB.z, 0x03020706u);              \
    a4 = dot2a(lo_, wpk, a4); a5 = dot2a(hi_, wpk, a5);                \
    lo_ = __builtin_amdgcn_perm(AA.w, BB.w, 0x01000504u);              \
    hi_ = __builtin_amdgcn_perm(AA.w, BB.w, 0x03020706u);              \
    a6 = dot2a(lo_, wpk, a6); a7 = dot2a(hi_, wpk, a7); }

  while (true) {
    const int n = node;
    int cn = cur_cn;
    int bpv = cur_bp;
    const int nxt = node + stride;
    if (nxt < N) {                              // prefetch NEXT node's bucket now
      cur_cn = cnt[nxt];
      cur_bp = bpad[(size_t)nxt * CAPB + l];
    }

    // ---- stage src ids (bucket <= 64 -> one step) ----
    int degb = cn < CAPB ? cn : CAPB;
    if (l < degb) sS[l] = bpv;
    int deg = degb;
    if (ovl) {                                   // never in practice
      int d = degb;
      if (l == 0) {
        for (int j = 0; j < ovl && d < 84; ++j) {
          int e = ovf[j];
          if (dstp[e] == n) sS[d++] = src[e];
        }
      }
      deg = __shfl(d, 0, 64);
    }

    // ---- pad edge count to multiple of 4 (ids now; weights zeroed after scores) ----
    int degp = (deg + 3) & ~3;
    if (l < degp - deg) sS[deg + l] = sS[0];

    // ---- issue first TWO gather load groups NOW (8 rows in flight under scores) ----
    uint4 A, B, A2, B2;
    if (degp > 0) {
      GLOAD(A, B, 0);
      if (degp > 4) GLOAD(A2, B2, 4);
    }

    // ---- scores: single pass, unnormalized exp stored fp16, deferred norm ----
    float er_h = er[n * 8 + (l & 7)];
    float psum = 0.f;
    for (int e = l >> 3; e < deg; e += 8) {      // lane = e*8 + h: el reads coalesced 32B
      int sidx = sS[e];
      float v = el[sidx * 8 + (l & 7)] + er_h;
      v = v >= 0.f ? v : 0.2f * v;
      float a = __expf(v);
      sWA[(l & 7) * WA + e] = __half_as_ushort(__float2half_rn(a));
      psum += a;
    }
    psum += __shfl_xor(psum, 8, 64);
    psum += __shfl_xor(psum, 16, 64);
    psum += __shfl_xor(psum, 32, 64);
    float rs = psum > 0.f ? __builtin_amdgcn_rcpf(psum) : 0.f;   // deg==0 -> scale 0

    // ---- zero pad weights ----
    { int pe = deg + (l >> 3); if (pe < degp) sWA[(l & 7) * WA + pe] = 0; }

    // ---- gather: depth-2 ping-pong, 4 edges/compute ----
    float a0 = 0.f, a1 = 0.f, a2 = 0.f, a3 = 0.f, a4 = 0.f, a5 = 0.f, a6 = 0.f, a7 = 0.f;
    if (degp > 0) {
      for (int i = 0;;) {
        GCOMP(A, B, i);
        if (i + 8 < degp) GLOAD(A, B, i + 8);
        if (i + 4 >= degp) break;
        GCOMP(A2, B2, i + 4);
        if (i + 12 < degp) GLOAD(A2, B2, i + 12);
        if (i + 8 >= degp) break;
        i += 8;
      }
    }
    // fold the two edge-subset halves
    a0 += __shfl_xor(a0, 32, 64); a1 += __shfl_xor(a1, 32, 64);
    a2 += __shfl_xor(a2, 32, 64); a3 += __shfl_xor(a3, 32, 64);
    a4 += __shfl_xor(a4, 32, 64); a5 += __shfl_xor(a5, 32, 64);
    a6 += __shfl_xor(a6, 32, 64); a7 += __shfl_xor(a7, 32, 64);

    // ---- normalize + bias + ELU (fast: __expf-1), pack h row to fp16 in LDS ----
    float sc = __shfl(rs, hh, 64);
    float o0 = fmaf(a0, sc, b0a.x), o1 = fmaf(a1, sc, b0a.y);
    float o2 = fmaf(a2, sc, b0a.z), o3 = fmaf(a3, sc, b0a.w);
    float o4 = fmaf(a4, sc, b0b.x), o5 = fmaf(a5, sc, b0b.y);
    float o6 = fmaf(a6, sc, b0b.z), o7 = fmaf(a7, sc, b0b.w);
    o0 = o0 > 0.f ? o0 : __expf(o0) - 1.f;  o1 = o1 > 0.f ? o1 : __expf(o1) - 1.f;
    o2 = o2 > 0.f ? o2 : __expf(o2) - 1.f;  o3 = o3 > 0.f ? o3 : __expf(o3) - 1.f;
    o4 = o4 > 0.f ? o4 : __expf(o4) - 1.f;  o5 = o5 > 0.f ? o5 : __expf(o5) - 1.f;
    o6 = o6 > 0.f ? o6 : __expf(o6) - 1.f;  o7 = o7 > 0.f ? o7 : __expf(o7) - 1.f;
    if (half == 0) {
      uint4 hp;
      hp.x = pkh2(o0, o1); hp.y = pkh2(o2, o3);
      hp.z = pkh2(o4, o5); hp.w = pkh2(o6, o7);
      *(uint4*)&s_h2[w][4 * sub] = hp;
    }
    asm volatile("s_waitcnt lgkmcnt(0)" ::: "memory");  // h-row visible wave-wide

    // ---- epilogue: f1 = h @ W1 via fp16 dot2 from LDS; el1/er1 dots ----
    const unsigned* wrow = &s_w1[sub * 132 + half * 64];
    const unsigned* hrow = &s_h2[w][half * 64];
    float p = 0.f;
#pragma unroll
    for (int j = 0; j < 64; j += 4) {
      uint4 wv = *(const uint4*)&wrow[j];
      uint4 hv = *(const uint4*)&hrow[j];
      p = dot2a(hv.x, wv.x, p);
      p = dot2a(hv.y, wv.y, p);
      p = dot2a(hv.z, wv.z, p);
      p = dot2a(hv.w, wv.w, p);
    }
    p += __shfl_xor(p, 32, 64);                  // fold k-halves -> f1[c], c = sub
    float pn = __shfl_xor(p, 1, 64);             // col-pair partner for fp16 pack
    float pl = p * al1c, pr = p * ar1c;
#pragma unroll
    for (int off = 16; off >= 1; off >>= 1) {
      pl += __shfl_xor(pl, off, 64);
      pr += __shfl_xor(pr, off, 64);
    }
    if (half == 0 && (sub & 1) == 0)
      *(unsigned*)(f1h + (size_t)n * 32 + sub) = pkh2(p, pn);
    if (l == 0) { el1[n] = pl; er1[n] = pr; }

    if (nxt >= N) break;
    node = nxt;
  }
#undef GLOAD
#undef GCOMP
}

// ---------------- fused edge kernel layer 1 (H=1, D=32, fp16 f1h) ----------------
// PERSISTENT: same scheme as k_fused0 — 1024x512, wave-per-node loop with
// next-node bucket prefetch. Zero barriers; all per-node LDS wave-private.
__global__ void k_fused1(const float* __restrict__ el, const float* __restrict__ er,
                         const unsigned short* __restrict__ f1h, const int* __restrict__ cnt,
                         const int* __restrict__ ovf_cnt, const int* __restrict__ bpad,
                         const int* __restrict__ ovf, const int* __restrict__ dstp,
                         const int* __restrict__ src, const float* __restrict__ b1,
                         float* __restrict__ h1, int N) {
  __shared__ int s_s[8][CAP1];            // staged src ids per node
  __shared__ unsigned s_wp[8][CAP1 / 2];  // fp16 weight pairs {a[i], a[i+8]} per 16-block

  const int t = threadIdx.x;
  const int g = __builtin_amdgcn_readfirstlane(t >> 6);
  const int lane = t & 63;
  const int stride = gridDim.x * 8;
  int node = blockIdx.x * 8 + g;
  if (node >= N) return;
  int* sS = s_s[g];
  unsigned* sWP = s_wp[g];

  const int es = lane >> 3, q = lane & 7;
  const int ovl = ovf_cnt[0];
  float4 bb = *(const float4*)(b1 + 4 * q);     // per-wave constant

  int cur_cn = cnt[node];
  int cur_bp = bpad[(size_t)node * CAPB + lane];

  while (true) {
    const int n = node;
    int cn = cur_cn;
    int bpv = cur_bp;
    const int nxt = node + stride;
    if (nxt < N) {                              // prefetch NEXT node's bucket now
      cur_cn = cnt[nxt];
      cur_bp = bpad[(size_t)nxt * CAPB + lane];
    }

    int degb = cn < CAPB ? cn : CAPB;
    if (lane < degb) sS[lane] = bpv;
    int deg = degb;
    if (ovl) {                            // never in practice
      int d = degb;
      if (lane == 0) {
        for (int j = 0; j < ovl && d < CAP1 - 16; ++j) {
          int e = ovf[j];
          if (dstp[e] == n) sS[d++] = src[e];
        }
      }
      deg = __shfl(d, 0, 64);
    }
    int degp = (deg + 15) & ~15;
    if (deg + lane < degp) sS[deg + lane] = sS[0];   // pad with valid row, zero weight

    // ---- issue first gather loads NOW (latency hides under scores) ----
    uint2 A, B;
    if (degp > 0) {
      A = *(const uint2*)(f1h + (size_t)sS[es] * 32 + 4 * q);
      B = *(const uint2*)(f1h + (size_t)sS[es + 8] * 32 + 4 * q);
    }

    // ---- scores: single pass; pair weights {a[i], a[i+8]} packed fp16 in LDS ----
    float er_n = er[n];
    float psum = 0.f;
    for (int i0 = 0; i0 < degp; i0 += 64) {
      int i = i0 + lane;
      float a = 0.f;
      if (i < deg) {
        float v = el[sS[i]] + er_n;
        v = v >= 0.f ? v : 0.2f * v;
        a = __expf(v);
        psum += a;
      }
      float an = __shfl_xor(a, 8, 64);
      if ((lane & 15) < 8 && i < degp)
        sWP[(i0 >> 1) + ((lane >> 4) << 3) + (lane & 7)] = pkh2(a, an);
    }
#pragma unroll
    for (int off = 32; off >= 1; off >>= 1) psum += __shfl_xor(psum, off, 64);
    float rs = psum > 0.f ? __builtin_amdgcn_rcpf(psum) : 0.f;   // deg==0 -> bias only

    // ---- gather: 16 edges/iter; lane handles cols 4q..4q+3 of edges es, es+8 ----
    float c0 = 0.f, c1 = 0.f, c2 = 0.f, c3 = 0.f;
    if (degp > 0) {
      for (int i0 = 0;;) {
        int in = i0 + 16;
        uint2 A2, B2;
        if (in < degp) {
          A2 = *(const uint2*)(f1h + (size_t)sS[in + es] * 32 + 4 * q);
          B2 = *(const uint2*)(f1h + (size_t)sS[in + es + 8] * 32 + 4 * q);
        }
        unsigned wp = sWP[(i0 >> 1) + es];
        unsigned lo = __builtin_amdgcn_perm(A.x, B.x, 0x01000504u);
        unsigned hi = __builtin_amdgcn_perm(A.x, B.x, 0x03020706u);
        c0 = dot2a(lo, wp, c0); c1 = dot2a(hi, wp, c1);
        lo = __builtin_amdgcn_perm(A.y, B.y, 0x01000504u);
        hi = __builtin_amdgcn_perm(A.y, B.y, 0x03020706u);
        c2 = dot2a(lo, wp, c2); c3 = dot2a(hi, wp, c3);
        if (in >= degp) break;
        i0 = in; A = A2; B = B2;
      }
    }
#pragma unroll
    for (int off = 8; off <= 32; off <<= 1) {
      c0 += __shfl_xor(c0, off, 64); c1 += __shfl_xor(c1, off, 64);
      c2 += __shfl_xor(c2, off, 64); c3 += __shfl_xor(c3, off, 64);
    }
    if (es == 0) {
      float4 o;
      o.x = fmaf(c0, rs, bb.x); o.y = fmaf(c1, rs, bb.y);
      o.z = fmaf(c2, rs, bb.z); o.w = fmaf(c3, rs, bb.w);
      ((float4*)(h1 + (size_t)n * 32))[q] = o;
    }

    if (nxt >= N) break;
    node = nxt;
  }
}

// ---------------- predictor (f64 acc — negligible cost, keeps margin) ----------------
__global__ void k_pred(const float* __restrict__ h1, const float* __restrict__ P1,
                       const float* __restrict__ pb1, const float* __restrict__ P2,
                       const float* __restrict__ pb2, const float* __restrict__ P3,
                       const float* __restrict__ pb3, float* __restrict__ out,
                       int num_edge, int total) {
  int t = threadIdx.x;
  int lane = t & 31, grp = t >> 5;
  int k = blockIdx.x * 8 + grp;
  int kk = k < total ? k : 0;
  float z;
  if (kk < num_edge) {
    z = h1[(size_t)kk * 32 + lane] * h1[(size_t)(kk + num_edge) * 32 + lane];
  } else {
    int i = kk - num_edge;
    int im = i;
    while (im >= num_edge) im -= num_edge;   // replaces integer % (ratio is small)
    z = h1[(size_t)im * 32 + lane] * h1[(size_t)(2 * num_edge + i) * 32 + lane];
  }
  double a1 = 0;
#pragma unroll
  for (int d = 0; d < 32; ++d)
    a1 += (double)__shfl(z, d, 32) * (double)P1[d * 32 + lane];
  float t1 = (float)(a1 + (double)pb1[lane]);
  t1 = t1 > 0.f ? t1 : 0.f;
  double a2 = 0;
#pragma unroll
  for (int d = 0; d < 32; ++d)
    a2 += (double)__shfl(t1, d, 32) * (double)P2[d * 32 + lane];
  float t2 = (float)(a2 + (double)pb2[lane]);
  t2 = t2 > 0.f ? t2 : 0.f;
  double a3 = (double)t2 * (double)P3[lane];
#pragma unroll
  for (int off = 16; off >= 1; off >>= 1) a3 += __shfl_xor(a3, off, 64);
  if (lane == 0 && k < total) out[k] = (float)(a3 + (double)pb3[0]);
}

extern "C" void kernel_launch(void* const* d_in, const int* in_sizes, int n_in,
                              void* d_out, int out_size, void* d_ws, size_t ws_size,
                              hipStream_t stream) {
  const float* x   = (const float*)d_in[0];
  const int*   src = (const int*)d_in[1];
  const int*   dst = (const int*)d_in[2];
  const float* W0  = (const float*)d_in[4];
  const float* al0 = (const float*)d_in[5];
  const float* ar0 = (const float*)d_in[6];
  const float* b0  = (const float*)d_in[7];
  const float* W1  = (const float*)d_in[8];
  const float* al1 = (const float*)d_in[9];
  const float* ar1 = (const float*)d_in[10];
  const float* b1  = (const float*)d_in[11];
  const float* P1  = (const float*)d_in[12];
  const float* pb1 = (const float*)d_in[13];
  const float* P2  = (const float*)d_in[14];
  const float* pb2 = (const float*)d_in[15];
  const float* P3  = (const float*)d_in[16];
  const float* pb3 = (const float*)d_in[17];

  int N = in_sizes[0] / 128;
  int E = in_sizes[1];
  int num_edge = N - out_size;   // N=(2+r)*ne, out=(1+r)*ne

  size_t off = 0;
  auto alloc = [&](size_t bytes) -> void* {
    void* p = (char*)d_ws + off;
    off += (bytes + 255) & ~(size_t)255;
    return p;
  };
  unsigned short* f0h = (unsigned short*)alloc((size_t)N * 256 * 2);   // fp16 gather table L0
  unsigned short* f1h = (unsigned short*)alloc((size_t)N * 32 * 2);    // fp16 gather table L1
  float* h1   = (float*)alloc((size_t)N * 32 * 4);
  float* el   = (float*)alloc((size_t)N * 8 * 4);
  float* er   = (float*)alloc((size_t)N * 8 * 4);
  float* el1  = (float*)alloc((size_t)N * 4);
  float* er1  = (float*)alloc((size_t)N * 4);
  int*   cnt  = (int*)alloc((size_t)(N + 1) * 4);   // [N] = overflow counter
  int*   bpad = (int*)alloc((size_t)N * CAPB * 4);
  int*   ovf  = (int*)alloc((size_t)E * 4);
  unsigned* W1ct = (unsigned*)alloc(4096 * 4);      // packed fp16 W1 [32][128] half2-pairs
  unsigned* W0h  = (unsigned*)alloc(16896 * 4);     // packed fp16 W0 + 512-dword prefetch pad
  if (off > ws_size) return;
  int* ovf_cnt = cnt + N;

  int ngemm = (N + G0_ROWS - 1) / G0_ROWS;    // 1563
  k_prep<<<128, 256, 0, stream>>>(W0, W1, W0h, W1ct, cnt, N + 1);
  k_gemm0_scatter<<<ngemm + NSCAT, 256, 0, stream>>>(x, W0h, al0, ar0, dst, src,
                                            f0h, el, er, cnt, ovf_cnt, bpad, ovf,
                                            N, E, ngemm);
  k_fused0<<<PBLK, 512, 0, stream>>>(el, er, f0h, cnt, ovf_cnt, bpad, ovf, dst,
                                     src, b0, W1ct, al1, ar1, f1h, el1, er1, N);
  k_fused1<<<PBLK, 512, 0, stream>>>(el1, er1, f1h, cnt, ovf_cnt, bpad, ovf, dst,
                                     src, b1, h1, N);
  k_pred<<<(out_size + 7) / 8, 256, 0, stream>>>(h1, P1, pb1, P2, pb2, P3, pb3,
                                                 (float*)d_out, num_edge, out_size);
}

// Round 15
// 257.620 us; speedup vs baseline: 1.0344x; 1.0344x over previous
//
#include <hip/hip_runtime.h>
#include <hip/hip_fp16.h>
#include <cmath>

#define CAPB 64    // padded bucket capacity; deg~Poisson(16), P(>64)~1e-21; overflow list for safety
#define CAPF 88    // staged edge capacity in k_fused0 (bucket + overflow + pad-to-4)
#define CAP1 96    // staged edge capacity in k_fused1 (bucket + overflow + pad-to-16)
#define WA   92    // s_wa per-head stride in halfwords (even, bank-spreading)
#define G0_ROWS 32 // rows per GEMM block: best measured point (r6/r7: gemm0 < 72us)
#define G0_PAD 36  // k2-row stride in dwords (multiple of 4 for b128-aligned reads)
#define NSCAT 1024 // scatter blocks

typedef _Float16 h2v __attribute__((ext_vector_type(2)));

__device__ __forceinline__ float dot2a(unsigned f, unsigned w, float acc) {
  return __builtin_amdgcn_fdot2(__builtin_bit_cast(h2v, f),
                                __builtin_bit_cast(h2v, w), acc, false);
}
__device__ __forceinline__ unsigned pkh2(float lo, float hi) {
  return (unsigned)__half_as_ushort(__float2half_rn(lo)) |
         ((unsigned)__half_as_ushort(__float2half_rn(hi)) << 16);
}

// ---------------- prep: zero cnt + pack W0/W1 into fp16 k-pair dwords ------------
__global__ void k_prep(const float* __restrict__ W0, const float* __restrict__ W1,
                       unsigned* __restrict__ W0h, unsigned* __restrict__ W1ct,
                       int* __restrict__ cnt, int Np1) {
  int gid = blockIdx.x * 256 + threadIdx.x;
  int stride = gridDim.x * 256;
  for (int i = gid; i < Np1; i += stride) cnt[i] = 0;
  if (gid < 16384) {
    int k2 = gid >> 8, c = gid & 255;
    W0h[gid] = pkh2(W0[(size_t)(2 * k2) * 256 + c], W0[(size_t)(2 * k2 + 1) * 256 + c]);
  } else if (gid < 20480) {
    int j = gid - 16384;
    int c = j >> 7, k2 = j & 127;
    W1ct[j] = pkh2(W1[(size_t)(2 * k2) * 32 + c], W1[(size_t)(2 * k2 + 1) * 32 + c]);
  } else if (gid < 20992) {
    W0h[gid - 20992 + 16896] = 0;   // zero the 2-row prefetch pad (k2 rows 64,65)
  }
}

// ---------------- merged kernel: gemm blocks OR scatter blocks (disjoint) ----------
// First ngemm blocks: GEMM0 tile (32 rows) via fp16 v_dot2 (packed W0h + fp16-pair
// LDS x), k2 loop software-pipelined depth 2 for W0h. Remaining blocks: edge
// scatter. fp32 accumulate; f0 stored FP16; el/er from fp32 accumulators.
__global__ void k_gemm0_scatter(const float* __restrict__ x, const unsigned* __restrict__ W0h,
                                const float* __restrict__ al, const float* __restrict__ ar,
                                const int* __restrict__ dst, const int* __restrict__ src,
                                unsigned short* __restrict__ f0h, float* __restrict__ el,
                                float* __restrict__ er, int* __restrict__ cnt,
                                int* __restrict__ ovf_cnt, int* __restrict__ bpad,
                                int* __restrict__ ovf, int N, int E, int ngemm) {
  __shared__ unsigned s_x2[66 * G0_PAD];   // k2 rows 0..63 data; rows 64,65 = prefetch pad
  int t = threadIdx.x;

  if (blockIdx.x >= ngemm) {
    int nscat = gridDim.x - ngemm;
    for (int e = (blockIdx.x - ngemm) * blockDim.x + t; e < E; e += nscat * blockDim.x) {
      int d = dst[e];
      int pos = atomicAdd(&cnt[d], 1);
      if (pos < CAPB) bpad[(size_t)d * CAPB + pos] = src[e];
      else { int op = atomicAdd(ovf_cnt, 1); ovf[op] = e; }
    }
    return;
  }

  // ---- gemm0 tile: 32 rows x 256 cols ----
  int w = t >> 6, l = t & 63;
  int row0 = blockIdx.x * G0_ROWS;
  {
    int row = t & 31, cg = t >> 5;           // cg 0..7: 16 cols each
    int grow = row0 + row; if (grow >= N) grow = N - 1;
    const float* xp = x + (size_t)grow * 128 + cg * 16;
    int k2b = cg * 8;
#pragma unroll
    for (int j = 0; j < 4; ++j) {
      float4 v = *(const float4*)(xp + 4 * j);
      s_x2[(k2b + 2 * j) * G0_PAD + row] = pkh2(v.x, v.y);
      s_x2[(k2b + 2 * j + 1) * G0_PAD + row] = pkh2(v.z, v.w);
    }
  }
  __syncthreads();

  float4 acc[8];
#pragma unroll
  for (int r = 0; r < 8; ++r) acc[r] = make_float4(0.f, 0.f, 0.f, 0.f);

  const unsigned* wp = W0h + 4 * l;
  int rbase = w * 8;

#define LDX(dstv, kk)                                              \
  { const unsigned* xk_ = &s_x2[(kk) * G0_PAD + rbase];            \
    *(uint4*)&dstv[0]  = *(const uint4*)(xk_);                     \
    *(uint4*)&dstv[4]  = *(const uint4*)(xk_ + 4); }
#define DOTS(xv, w4)                                               \
  _Pragma("unroll")                                                \
  for (int r = 0; r < 8; ++r) {                                    \
    acc[r].x = dot2a(xv[r], w4.x, acc[r].x);                       \
    acc[r].y = dot2a(xv[r], w4.y, acc[r].y);                       \
    acc[r].z = dot2a(xv[r], w4.z, acc[r].z);                       \
    acc[r].w = dot2a(xv[r], w4.w, acc[r].w);                       \
  }

  unsigned xA[8], xB[8];
  uint4 wA = *(const uint4*)(wp);
  uint4 wB = *(const uint4*)(wp + 256);
  LDX(xA, 0);
#pragma unroll 2
  for (int k2 = 0; k2 < 64; k2 += 2) {
    uint4 wC = *(const uint4*)(wp + (size_t)(k2 + 2) * 256);  // pad rows safe
    uint4 wD = *(const uint4*)(wp + (size_t)(k2 + 3) * 256);
    LDX(xB, k2 + 1);
    DOTS(xA, wA);
    LDX(xA, k2 + 2);                                          // pad row safe in LDS
    DOTS(xB, wB);
    wA = wC; wB = wD;
  }
#undef LDX
#undef DOTS

  int hh = l >> 3;
  float4 al4 = *(const float4*)(al + 4 * l);
  float4 ar4 = *(const float4*)(ar + 4 * l);
#pragma unroll
  for (int r = 0; r < 8; ++r) {
    int row = row0 + rbase + r;
    float4 f = acc[r];
    if (row < N) {
      ushort4 h4;
      h4.x = __half_as_ushort(__float2half_rn(f.x));
      h4.y = __half_as_ushort(__float2half_rn(f.y));
      h4.z = __half_as_ushort(__float2half_rn(f.z));
      h4.w = __half_as_ushort(__float2half_rn(f.w));
      *(ushort4*)(f0h + (size_t)row * 256 + 4 * l) = h4;
    }
    float pl = fmaf(f.x, al4.x, fmaf(f.y, al4.y, fmaf(f.z, al4.z, f.w * al4.w)));
    float pr = fmaf(f.x, ar4.x, fmaf(f.y, ar4.y, fmaf(f.z, ar4.z, f.w * ar4.w)));
#pragma unroll
    for (int off = 4; off >= 1; off >>= 1) {
      pl += __shfl_xor(pl, off, 64);
      pr += __shfl_xor(pr, off, 64);
    }
    if ((l & 7) == 0 && row < N) {
      el[row * 8 + hh] = pl;
      er[row * 8 + hh] = pr;
    }
  }
}

// ---------------- fused edge kernel layer 0 + layer-1 projection -------------------
// One WAVE per node, EIGHT nodes per 512-thread block. All per-node LDS is
// wave-private: no per-node barriers. Gather software-pipelined DEPTH 2 (edges i,
// i+4 resident; i+8, i+12 in flight) with ping-pong register pairs (no copies);
// 8 rows in flight during the scores phase. ELU via __expf(o)-1.
__global__ void k_fused0(const float* __restrict__ el, const float* __restrict__ er,
                         const unsigned short* __restrict__ f0h, const int* __restrict__ cnt,
                         const int* __restrict__ ovf_cnt, const int* __restrict__ bpad,
                         const int* __restrict__ ovf, const int* __restrict__ dstp,
                         const int* __restrict__ src, const float* __restrict__ b0,
                         const unsigned* __restrict__ W1ct, const float* __restrict__ al1,
                         const float* __restrict__ ar1, unsigned short* __restrict__ f1h,
                         float* __restrict__ el1, float* __restrict__ er1, int N) {
  __shared__ unsigned s_w1[32 * 132];          // 16896 B, W1 half2-pairs [c][k2], stride 132
  __shared__ unsigned short s_wa[8][8 * WA];   // 11776 B, fp16 softmax weights per node
  __shared__ int s_s[8][CAPF];                 //  2816 B, staged src ids per node
  __shared__ unsigned s_h2[8][128];            //  4096 B, fp16-packed h row per node

  const int t = threadIdx.x;
  // ---- stage packed W1 into LDS (pad stride 132 for bank spread) ----
  for (int base = t * 4; base < 4096; base += 2048) {
    uint4 v = *(const uint4*)&W1ct[base];
    int c = base >> 7, k2 = base & 127;
    *(uint4*)&s_w1[c * 132 + k2] = v;
  }
  __syncthreads();

  const int w = __builtin_amdgcn_readfirstlane(t >> 6);
  const int l = t & 63;
  const int n = blockIdx.x * 8 + w;
  if (n >= N) return;

  int* sS = s_s[w];
  unsigned short* sWA = s_wa[w];

  const int sub = l & 31, half = l >> 5, hh = sub >> 2;
  // per-wave constant preloads (issue early, consumed late)
  float4 b0a = ((const float4*)(b0 + 8 * sub))[0];
  float4 b0b = ((const float4*)(b0 + 8 * sub))[1];
  float al1c = al1[sub], ar1c = ar1[sub];

  // ---- stage src ids (bucket <= 64 -> one step) ----
  int cn = cnt[n];
  int degb = cn < CAPB ? cn : CAPB;
  if (l < degb) sS[l] = bpad[(size_t)n * CAPB + l];
  int deg = degb;
  int ovl = ovf_cnt[0];
  if (ovl) {                                   // never in practice
    int d = degb;
    if (l == 0) {
      for (int j = 0; j < ovl && d < 84; ++j) {
        int e = ovf[j];
        if (dstp[e] == n) sS[d++] = src[e];
      }
    }
    deg = __shfl(d, 0, 64);
  }

  // ---- pad edge count to multiple of 4 (ids now; weights zeroed after scores) ----
  int degp = (deg + 3) & ~3;
  if (l < degp - deg) sS[deg + l] = sS[0];

#define GLOAD(AA, BB, ii)                                              \
  { int2 s_ = *(const int2*)&sS[(ii) + 2 * half];                      \
    AA = ((const uint4*)(f0h + (size_t)s_.x * 256))[sub];              \
    BB = ((const uint4*)(f0h + (size_t)s_.y * 256))[sub]; }
#define GCOMP(AA, BB, ii)                                              \
  { unsigned wpk = *(const unsigned*)&sWA[hh * WA + (ii) + 2 * half];  \
    unsigned lo_, hi_;                                                 \
    lo_ = __builtin_amdgcn_perm(AA.x, BB.x, 0x01000504u);              \
    hi_ = __builtin_amdgcn_perm(AA.x, BB.x, 0x03020706u);              \
    a0 = dot2a(lo_, wpk, a0); a1 = dot2a(hi_, wpk, a1);                \
    lo_ = __builtin_amdgcn_perm(AA.y, BB.y, 0x01000504u);              \
    hi_ = __builtin_amdgcn_perm(AA.y, BB.y, 0x03020706u);              \
    a2 = dot2a(lo_, wpk, a2); a3 = dot2a(hi_, wpk, a3);                \
    lo_ = __builtin_amdgcn_perm(AA.z, BB.z, 0x01000504u);              \
    hi_ = __builtin_amdgcn_perm(AA.z, BB.z, 0x03020706u);              \
    a4 = dot2a(lo_, wpk, a4); a5 = dot2a(hi_, wpk, a5);                \
    lo_ = __builtin_amdgcn_perm(AA.w, BB.w, 0x01000504u);              \
    hi_ = __builtin_amdgcn_perm(AA.w, BB.w, 0x03020706u);              \
    a6 = dot2a(lo_, wpk, a6); a7 = dot2a(hi_, wpk, a7); }

  // ---- issue first TWO gather load groups NOW (8 rows in flight under scores) ----
  uint4 A, B, A2, B2;
  if (degp > 0) {
    GLOAD(A, B, 0);
    if (degp > 4) GLOAD(A2, B2, 4);
  }

  // ---- scores: single pass, no max subtraction (|v| ~ O(1), exp fp32-safe),
  //      unnormalized exp stored fp16; normalization deferred to accumulator scale ----
  float er_h = er[n * 8 + (l & 7)];
  float psum = 0.f;
  for (int e = l >> 3; e < deg; e += 8) {      // lane = e*8 + h: el reads coalesced 32B
    int sidx = sS[e];
    float v = el[sidx * 8 + (l & 7)] + er_h;
    v = v >= 0.f ? v : 0.2f * v;
    float a = __expf(v);
    sWA[(l & 7) * WA + e] = __half_as_ushort(__float2half_rn(a));
    psum += a;
  }
  psum += __shfl_xor(psum, 8, 64);
  psum += __shfl_xor(psum, 16, 64);
  psum += __shfl_xor(psum, 32, 64);
  float rs = psum > 0.f ? __builtin_amdgcn_rcpf(psum) : 0.f;   // deg==0 -> scale 0

  // ---- zero pad weights ----
  { int pe = deg + (l >> 3); if (pe < degp) sWA[(l & 7) * WA + pe] = 0; }

  // ---- gather: depth-2 ping-pong, 4 edges/compute; lanes<32 take e,e+1;
  //      lanes>=32 take e+2,e+3; lane covers elems 8*sub..8*sub+7 (head hh) ----
  float a0 = 0.f, a1 = 0.f, a2 = 0.f, a3 = 0.f, a4 = 0.f, a5 = 0.f, a6 = 0.f, a7 = 0.f;
  if (degp > 0) {
    for (int i = 0;;) {
      GCOMP(A, B, i);
      if (i + 8 < degp) GLOAD(A, B, i + 8);
      if (i + 4 >= degp) break;
      GCOMP(A2, B2, i + 4);
      if (i + 12 < degp) GLOAD(A2, B2, i + 12);
      if (i + 8 >= degp) break;
      i += 8;
    }
  }
#undef GLOAD
#undef GCOMP
  // fold the two edge-subset halves
  a0 += __shfl_xor(a0, 32, 64); a1 += __shfl_xor(a1, 32, 64);
  a2 += __shfl_xor(a2, 32, 64); a3 += __shfl_xor(a3, 32, 64);
  a4 += __shfl_xor(a4, 32, 64); a5 += __shfl_xor(a5, 32, 64);
  a6 += __shfl_xor(a6, 32, 64); a7 += __shfl_xor(a7, 32, 64);

  // ---- normalize + bias + ELU (fast: __expf-1), pack h row to fp16 in LDS ----
  float sc = __shfl(rs, hh, 64);
  float o0 = fmaf(a0, sc, b0a.x), o1 = fmaf(a1, sc, b0a.y);
  float o2 = fmaf(a2, sc, b0a.z), o3 = fmaf(a3, sc, b0a.w);
  float o4 = fmaf(a4, sc, b0b.x), o5 = fmaf(a5, sc, b0b.y);
  float o6 = fmaf(a6, sc, b0b.z), o7 = fmaf(a7, sc, b0b.w);
  o0 = o0 > 0.f ? o0 : __expf(o0) - 1.f;  o1 = o1 > 0.f ? o1 : __expf(o1) - 1.f;
  o2 = o2 > 0.f ? o2 : __expf(o2) - 1.f;  o3 = o3 > 0.f ? o3 : __expf(o3) - 1.f;
  o4 = o4 > 0.f ? o4 : __expf(o4) - 1.f;  o5 = o5 > 0.f ? o5 : __expf(o5) - 1.f;
  o6 = o6 > 0.f ? o6 : __expf(o6) - 1.f;  o7 = o7 > 0.f ? o7 : __expf(o7) - 1.f;
  if (half == 0) {
    uint4 hp;
    hp.x = pkh2(o0, o1); hp.y = pkh2(o2, o3);
    hp.z = pkh2(o4, o5); hp.w = pkh2(o6, o7);
    *(uint4*)&s_h2[w][4 * sub] = hp;
  }
  asm volatile("s_waitcnt lgkmcnt(0)" ::: "memory");  // h-row visible wave-wide

  // ---- epilogue: f1 = h @ W1 via fp16 dot2 from LDS; el1/er1 dots ----
  const unsigned* wrow = &s_w1[sub * 132 + half * 64];
  const unsigned* hrow = &s_h2[w][half * 64];
  float p = 0.f;
#pragma unroll
  for (int j = 0; j < 64; j += 4) {
    uint4 wv = *(const uint4*)&wrow[j];
    uint4 hv = *(const uint4*)&hrow[j];
    p = dot2a(hv.x, wv.x, p);
    p = dot2a(hv.y, wv.y, p);
    p = dot2a(hv.z, wv.z, p);
    p = dot2a(hv.w, wv.w, p);
  }
  p += __shfl_xor(p, 32, 64);                  // fold k-halves -> f1[c], c = sub
  float pn = __shfl_xor(p, 1, 64);             // col-pair partner for fp16 pack
  float pl = p * al1c, pr = p * ar1c;
#pragma unroll
  for (int off = 16; off >= 1; off >>= 1) {
    pl += __shfl_xor(pl, off, 64);
    pr += __shfl_xor(pr, off, 64);
  }
  if (half == 0 && (sub & 1) == 0)
    *(unsigned*)(f1h + (size_t)n * 32 + sub) = pkh2(p, pn);
  if (l == 0) { el1[n] = pl; er1[n] = pr; }
}

// ---------------- fused edge kernel layer 1 (H=1, D=32, fp16 f1h) ----------------
// One WAVE per node, EIGHT nodes per 512-thread block, zero barriers, single-pass
// __expf softmax with deferred normalization. First gather loads issued before the
// scores phase (deg<=16 common case: ALL gather loads in flight during scores).
__global__ void k_fused1(const float* __restrict__ el, const float* __restrict__ er,
                         const unsigned short* __restrict__ f1h, const int* __restrict__ cnt,
                         const int* __restrict__ ovf_cnt, const int* __restrict__ bpad,
                         const int* __restrict__ ovf, const int* __restrict__ dstp,
                         const int* __restrict__ src, const float* __restrict__ b1,
                         float* __restrict__ h1, int N) {
  __shared__ int s_s[8][CAP1];            // staged src ids per node
  __shared__ unsigned s_wp[8][CAP1 / 2];  // fp16 weight pairs {a[i], a[i+8]} per 16-block

  const int t = threadIdx.x;
  const int g = __builtin_amdgcn_readfirstlane(t >> 6);
  const int lane = t & 63;
  int n = blockIdx.x * 8 + g;
  int nn = n < N ? n : N - 1;
  int* sS = s_s[g];
  unsigned* sWP = s_wp[g];

  int cn = cnt[nn];
  int degb = cn < CAPB ? cn : CAPB;
  if (lane < degb) sS[lane] = bpad[(size_t)nn * CAPB + lane];
  int deg = degb;
  int ovl = ovf_cnt[0];
  if (ovl) {                            // never in practice
    int d = degb;
    if (lane == 0) {
      for (int j = 0; j < ovl && d < CAP1 - 16; ++j) {
        int e = ovf[j];
        if (dstp[e] == nn) sS[d++] = src[e];
      }
    }
    deg = __shfl(d, 0, 64);
  }
  int degp = (deg + 15) & ~15;
  if (deg + lane < degp) sS[deg + lane] = sS[0];   // pad with valid row, zero weight

  // ---- issue first gather loads NOW (latency hides under scores) ----
  const int es = lane >> 3, q = lane & 7;
  uint2 A, B;
  if (degp > 0) {
    A = *(const uint2*)(f1h + (size_t)sS[es] * 32 + 4 * q);
    B = *(const uint2*)(f1h + (size_t)sS[es + 8] * 32 + 4 * q);
  }

  // ---- scores: single pass; pair weights {a[i], a[i+8]} packed fp16 in LDS ----
  float er_n = er[nn];
  float psum = 0.f;
  for (int i0 = 0; i0 < degp; i0 += 64) {
    int i = i0 + lane;
    float a = 0.f;
    if (i < deg) {
      float v = el[sS[i]] + er_n;
      v = v >= 0.f ? v : 0.2f * v;
      a = __expf(v);
      psum += a;
    }
    float an = __shfl_xor(a, 8, 64);
    if ((lane & 15) < 8 && i < degp)
      sWP[(i0 >> 1) + ((lane >> 4) << 3) + (lane & 7)] = pkh2(a, an);
  }
#pragma unroll
  for (int off = 32; off >= 1; off >>= 1) psum += __shfl_xor(psum, off, 64);
  float rs = psum > 0.f ? __builtin_amdgcn_rcpf(psum) : 0.f;   // deg==0 -> bias only

  // ---- gather: 16 edges/iter; lane handles cols 4q..4q+3 of edges es, es+8 ----
  float c0 = 0.f, c1 = 0.f, c2 = 0.f, c3 = 0.f;
  if (degp > 0) {
    for (int i0 = 0;;) {
      int in = i0 + 16;
      uint2 A2, B2;
      if (in < degp) {
        A2 = *(const uint2*)(f1h + (size_t)sS[in + es] * 32 + 4 * q);
        B2 = *(const uint2*)(f1h + (size_t)sS[in + es + 8] * 32 + 4 * q);
      }
      unsigned wp = sWP[(i0 >> 1) + es];
      unsigned lo = __builtin_amdgcn_perm(A.x, B.x, 0x01000504u);
      unsigned hi = __builtin_amdgcn_perm(A.x, B.x, 0x03020706u);
      c0 = dot2a(lo, wp, c0); c1 = dot2a(hi, wp, c1);
      lo = __builtin_amdgcn_perm(A.y, B.y, 0x01000504u);
      hi = __builtin_amdgcn_perm(A.y, B.y, 0x03020706u);
      c2 = dot2a(lo, wp, c2); c3 = dot2a(hi, wp, c3);
      if (in >= degp) break;
      i0 = in; A = A2; B = B2;
    }
  }
#pragma unroll
  for (int off = 8; off <= 32; off <<= 1) {
    c0 += __shfl_xor(c0, off, 64); c1 += __shfl_xor(c1, off, 64);
    c2 += __shfl_xor(c2, off, 64); c3 += __shfl_xor(c3, off, 64);
  }
  if (es == 0 && n < N) {
    float4 b = *(const float4*)(b1 + 4 * q);
    float4 o;
    o.x = fmaf(c0, rs, b.x); o.y = fmaf(c1, rs, b.y);
    o.z = fmaf(c2, rs, b.z); o.w = fmaf(c3, rs, b.w);
    ((float4*)(h1 + (size_t)n * 32))[q] = o;
  }
}

// ---------------- predictor (f64 acc — negligible cost, keeps margin) ----------------
__global__ void k_pred(const float* __restrict__ h1, const float* __restrict__ P1,
                       const float* __restrict__ pb1, const float* __restrict__ P2,
                       const float* __restrict__ pb2, const float* __restrict__ P3,
                       const float* __restrict__ pb3, float* __restrict__ out,
                       int num_edge, int total) {
  int t = threadIdx.x;
  int lane = t & 31, grp = t >> 5;
  int k = blockIdx.x * 8 + grp;
  int kk = k < total ? k : 0;
  float z;
  if (kk < num_edge) {
    z = h1[(size_t)kk * 32 + lane] * h1[(size_t)(kk + num_edge) * 32 + lane];
  } else {
    int i = kk - num_edge;
    int im = i;
    while (im >= num_edge) im -= num_edge;   // replaces integer % (ratio is small)
    z = h1[(size_t)im * 32 + lane] * h1[(size_t)(2 * num_edge + i) * 32 + lane];
  }
  double a1 = 0;
#pragma unroll
  for (int d = 0; d < 32; ++d)
    a1 += (double)__shfl(z, d, 32) * (double)P1[d * 32 + lane];
  float t1 = (float)(a1 + (double)pb1[lane]);
  t1 = t1 > 0.f ? t1 : 0.f;
  double a2 = 0;
#pragma unroll
  for (int d = 0; d < 32; ++d)
    a2 += (double)__shfl(t1, d, 32) * (double)P2[d * 32 + lane];
  float t2 = (float)(a2 + (double)pb2[lane]);
  t2 = t2 > 0.f ? t2 : 0.f;
  double a3 = (double)t2 * (double)P3[lane];
#pragma unroll
  for (int off = 16; off >= 1; off >>= 1) a3 += __shfl_xor(a3, off, 64);
  if (lane == 0 && k < total) out[k] = (float)(a3 + (double)pb3[0]);
}

extern "C" void kernel_launch(void* const* d_in, const int* in_sizes, int n_in,
                              void* d_out, int out_size, void* d_ws, size_t ws_size,
                              hipStream_t stream) {
  const float* x   = (const float*)d_in[0];
  const int*   src = (const int*)d_in[1];
  const int*   dst = (const int*)d_in[2];
  const float* W0  = (const float*)d_in[4];
  const float* al0 = (const float*)d_in[5];
  const float* ar0 = (const float*)d_in[6];
  const float* b0  = (const float*)d_in[7];
  const float* W1  = (const float*)d_in[8];
  const float* al1 = (const float*)d_in[9];
  const float* ar1 = (const float*)d_in[10];
  const float* b1  = (const float*)d_in[11];
  const float* P1  = (const float*)d_in[12];
  const float* pb1 = (const float*)d_in[13];
  const float* P2  = (const float*)d_in[14];
  const float* pb2 = (const float*)d_in[15];
  const float* P3  = (const float*)d_in[16];
  const float* pb3 = (const float*)d_in[17];

  int N = in_sizes[0] / 128;
  int E = in_sizes[1];
  int num_edge = N - out_size;   // N=(2+r)*ne, out=(1+r)*ne

  size_t off = 0;
  auto alloc = [&](size_t bytes) -> void* {
    void* p = (char*)d_ws + off;
    off += (bytes + 255) & ~(size_t)255;
    return p;
  };
  unsigned short* f0h = (unsigned short*)alloc((size_t)N * 256 * 2);   // fp16 gather table L0
  unsigned short* f1h = (unsigned short*)alloc((size_t)N * 32 * 2);    // fp16 gather table L1
  float* h1   = (float*)alloc((size_t)N * 32 * 4);
  float* el   = (float*)alloc((size_t)N * 8 * 4);
  float* er   = (float*)alloc((size_t)N * 8 * 4);
  float* el1  = (float*)alloc((size_t)N * 4);
  float* er1  = (float*)alloc((size_t)N * 4);
  int*   cnt  = (int*)alloc((size_t)(N + 1) * 4);   // [N] = overflow counter
  int*   bpad = (int*)alloc((size_t)N * CAPB * 4);
  int*   ovf  = (int*)alloc((size_t)E * 4);
  unsigned* W1ct = (unsigned*)alloc(4096 * 4);      // packed fp16 W1 [32][128] half2-pairs
  unsigned* W0h  = (unsigned*)alloc(16896 * 4);     // packed fp16 W0 + 512-dword prefetch pad
  if (off > ws_size) return;
  int* ovf_cnt = cnt + N;

  int ngemm = (N + G0_ROWS - 1) / G0_ROWS;    // 1563
  k_prep<<<128, 256, 0, stream>>>(W0, W1, W0h, W1ct, cnt, N + 1);
  k_gemm0_scatter<<<ngemm + NSCAT, 256, 0, stream>>>(x, W0h, al0, ar0, dst, src,
                                            f0h, el, er, cnt, ovf_cnt, bpad, ovf,
                                            N, E, ngemm);
  k_fused0<<<(N + 7) / 8, 512, 0, stream>>>(el, er, f0h, cnt, ovf_cnt, bpad, ovf, dst,
                                            src, b0, W1ct, al1, ar1, f1h, el1, er1, N);
  k_fused1<<<(N + 7) / 8, 512, 0, stream>>>(el1, er1, f1h, cnt, ovf_cnt, bpad, ovf, dst,
                                            src, b1, h1, N);
  k_pred<<<(out_size + 7) / 8, 256, 0, stream>>>(h1, P1, pb1, P2, pb2, P3, pb3,
                                                 (float*)d_out, num_edge, out_size);
}